// Round 2
// baseline (191.046 us; speedup 1.0000x reference)
//
#include <hip/hip_runtime.h>
#include <math.h>

// Problem constants
constexpr int NROI = 2048;  // N
constexpr int CDIM = 1024;  // C
constexpr int NG   = 16;    // groups
constexpr int DH   = 64;    // per-group dim

typedef __attribute__((ext_vector_type(8))) short short8;    // 8 bf16 (4 VGPRs)
typedef __attribute__((ext_vector_type(4))) float floatx4;   // MFMA C/D frag

#define MFMA_BF16(a, b, c) __builtin_amdgcn_mfma_f32_16x16x32_bf16((a), (b), (c), 0, 0, 0)

// fp32 -> bf16 round-to-nearest-even
__device__ __forceinline__ short f2bf(float f) {
  unsigned u = __float_as_uint(f);
  unsigned r = 0x7fffu + ((u >> 16) & 1u);
  return (short)((u + r) >> 16);
}
__device__ __forceinline__ float bf2f(unsigned short u) {
  return __uint_as_float(((unsigned)u) << 16);
}
__device__ __forceinline__ unsigned pack2(float a, float b) {
  return (unsigned)(unsigned short)f2bf(a) | ((unsigned)(unsigned short)f2bf(b) << 16);
}

// HW packed fp32->bf16 convert: dst.lo = bf16(lo), dst.hi = bf16(hi)
__device__ __forceinline__ unsigned cvtpk_bf16(float lo, float hi) {
  unsigned r;
  asm("v_cvt_pk_bf16_f32 %0, %1, %2" : "=v"(r) : "v"(lo), "v"(hi));
  return r;
}

// 2^x via v_exp_f32
__device__ __forceinline__ float fexp2(float x) {
#if __has_builtin(__builtin_amdgcn_exp2f)
  return __builtin_amdgcn_exp2f(x);
#else
  return __expf(x * 0.69314718056f);
#endif
}

// async global->LDS, 16B per lane; LDS dest = wave-uniform base + lane*16
typedef __attribute__((address_space(1))) void GV;
typedef __attribute__((address_space(3))) void LV;
__device__ __forceinline__ void gl2lds16(const void* g, void* l) {
  __builtin_amdgcn_global_load_lds((GV*)g, (LV*)l, 16, 0, 0);
}

// bf16 relu on a packed short8 (sign-bit based; exact)
__device__ __forceinline__ short8 brelu(short8 v) {
  union { short8 s; unsigned u[4]; } x; x.s = v;
#pragma unroll
  for (int i = 0; i < 4; ++i) {
    unsigned m = (x.u[i] >> 15) & 0x10001u;
    x.u[i] &= ~(m * 0xFFFFu);
  }
  return x.s;
}

// --- key-position permutation -------------------------------------------------
// The attention kernel computes S^T = mfma(K, Q), so a lane ends up holding
// P values for keys 16ct + 4qq + r. The PV contraction is invariant under a
// permutation of the MFMA k-slots, so we store V (zT) and the bias matrix with
// their key axis permuted such that P packs in-lane with NO cross-lane moves:
//   position p(k) within each 32-key block = ((k>>2)&3)*8 + ((k>>4)&1)*4 + (k&3)
// Groups of 4 consecutive keys (4-aligned) stay 4 consecutive positions, so the
// producers (gemm64's transposed store, iou4's uint2 store) just remap the
// store address at zero cost.
__device__ __forceinline__ int keypos(int k) {
  return (k & ~31) | (((k >> 2) & 3) << 3) | (((k >> 4) & 1) << 2);
}

// ---------------- streaming fp32 -> bf16 conversion (x + 3 weights) ----------------
__global__ __launch_bounds__(256) void convert_kernel(
    const float* __restrict__ in_x, const float* __restrict__ W0,
    const float* __restrict__ W1, const float* __restrict__ Wout,
    short* __restrict__ xin_b, short* __restrict__ W0b,
    short* __restrict__ W1b, short* __restrict__ Woutb)
{
  const int i = blockIdx.x * 256 + threadIdx.x;   // float4 units
  {
    const float4 v = ((const float4*)in_x)[i];
    uint2 u; u.x = pack2(v.x, v.y); u.y = pack2(v.z, v.w);
    ((uint2*)xin_b)[i] = u;
  }
  if (i < 262144) {
    float4 v = ((const float4*)W0)[i];
    uint2 u; u.x = pack2(v.x, v.y); u.y = pack2(v.z, v.w);
    ((uint2*)W0b)[i] = u;
    v = ((const float4*)W1)[i];
    u.x = pack2(v.x, v.y); u.y = pack2(v.z, v.w);
    ((uint2*)W1b)[i] = u;
    v = ((const float4*)Wout)[i];
    u.x = pack2(v.x, v.y); u.y = pack2(v.z, v.w);
    ((uint2*)Woutb)[i] = u;
  }
}

// ---------------- iou+1e-6 matrix, 4 keys/thread, rcp divide, 8-B stores ----------------
// Stores in KEY-PERMUTED layout (see keypos above).
__global__ __launch_bounds__(256) void iou4_kernel(const float* __restrict__ rois,
                                                   unsigned short* __restrict__ biasb)
{
  const int q  = blockIdx.y;
  const int k0 = (blockIdx.x * 256 + threadIdx.x) * 4;
  const float qx1 = rois[q * 5 + 1], qy1 = rois[q * 5 + 2];
  const float qx2 = rois[q * 5 + 3], qy2 = rois[q * 5 + 4];
  const float qa = (qx2 - qx1 + 1.f) * (qy2 - qy1 + 1.f);
  float v[4];
#pragma unroll
  for (int j = 0; j < 4; ++j) {
    const int k = k0 + j;
    const float kx1 = rois[k * 5 + 1], ky1 = rois[k * 5 + 2];
    const float kx2 = rois[k * 5 + 3], ky2 = rois[k * 5 + 4];
    const float ka = (kx2 - kx1 + 1.f) * (ky2 - ky1 + 1.f);
    float iw = fminf(qx2, kx2) - fmaxf(qx1, kx1) + 1.f;
    float ih = fminf(qy2, ky2) - fmaxf(qy1, ky1) + 1.f;
    iw = fmaxf(iw, 0.f); ih = fmaxf(ih, 0.f);
    const float inter = iw * ih;
    v[j] = inter * __builtin_amdgcn_rcpf(qa + ka - inter) + 1e-6f;
  }
  uint2 u; u.x = pack2(v[0], v[1]); u.y = pack2(v[2], v[3]);
  *(uint2*)&biasb[(size_t)q * NROI + keypos(k0)] = u;
}

// ---------------- 64x64 double-buffered GEMM, high occupancy ----------------
// FUSED=1: blockIdx.x<16 -> t0 = relu(x)@W0^T+b0 (row-major); else
//          zT = (x@Wout^T)^T (transposed out, KEY-PERMUTED rows). grid (32,32).
// FUSED=0: C = relu(A)@B^T + bias (row-major). grid (16,32).
template <int FUSED>
__global__ __launch_bounds__(256, 4) void gemm64(
    const short* __restrict__ A, const short* __restrict__ Ba,
    const short* __restrict__ Bb, const float* __restrict__ bias,
    short* __restrict__ outRM, short* __restrict__ outTR)
{
  __shared__ short As[2][8 * 512];
  __shared__ short Bs[2][8 * 512];
  const int t = threadIdx.x, w = t >> 6, lane = t & 63;
  const int wm = w >> 1, wn = w & 1;
  const int row0 = blockIdx.y * 64;
  bool isW0; int col0; const short* B;
  if (FUSED) {
    isW0 = blockIdx.x < 16;
    col0 = (blockIdx.x & 15) * 64;
    B = isW0 ? Ba : Bb;
  } else {
    isW0 = true; col0 = blockIdx.x * 64; B = Ba;
  }
  const bool doRelu = FUSED ? isW0 : true;
  const int rlo = lane & 15, khi = (lane >> 4) * 8;

  floatx4 acc[2][2];
#pragma unroll
  for (int i = 0; i < 2; ++i)
#pragma unroll
    for (int j = 0; j < 2; ++j) acc[i][j] = (floatx4){0.f, 0.f, 0.f, 0.f};

#pragma unroll
  for (int kh = 0; kh < 2; ++kh) {
    const int f = w * 2 + kh;
    gl2lds16(A + (size_t)(row0 + w * 16 + rlo) * CDIM + kh * 32 + khi, &As[0][f * 512]);
    gl2lds16(B + (size_t)(col0 + w * 16 + rlo) * CDIM + kh * 32 + khi, &Bs[0][f * 512]);
  }
  __syncthreads();

  for (int it = 0; it < 16; ++it) {
    const int p = it & 1;
    if (it < 15) {
      const int k1 = (it + 1) * 64;
#pragma unroll
      for (int kh = 0; kh < 2; ++kh) {
        const int f = w * 2 + kh;
        gl2lds16(A + (size_t)(row0 + w * 16 + rlo) * CDIM + k1 + kh * 32 + khi,
                 &As[1 - p][f * 512]);
        gl2lds16(B + (size_t)(col0 + w * 16 + rlo) * CDIM + k1 + kh * 32 + khi,
                 &Bs[1 - p][f * 512]);
      }
    }
#pragma unroll
    for (int kh = 0; kh < 2; ++kh) {
      short8 a[2], bf[2];
#pragma unroll
      for (int i = 0; i < 2; ++i) {
        a[i] = *(const short8*)&As[p][((wm * 2 + i) * 2 + kh) * 512 + lane * 8];
        if (doRelu) a[i] = brelu(a[i]);
      }
#pragma unroll
      for (int j = 0; j < 2; ++j)
        bf[j] = *(const short8*)&Bs[p][((wn * 2 + j) * 2 + kh) * 512 + lane * 8];
#pragma unroll
      for (int i = 0; i < 2; ++i)
#pragma unroll
        for (int j = 0; j < 2; ++j)
          acc[i][j] = MFMA_BF16(a[i], bf[j], acc[i][j]);
    }
    __syncthreads();
  }

  const int colL = lane & 15, qq = lane >> 4;
  if (!FUSED || isW0) {
    float bj[2];
    bj[0] = bias[col0 + wn * 32 + colL];
    bj[1] = bias[col0 + wn * 32 + 16 + colL];
#pragma unroll
    for (int i = 0; i < 2; ++i)
#pragma unroll
      for (int j = 0; j < 2; ++j)
#pragma unroll
        for (int r = 0; r < 4; ++r) {
          const int row = row0 + wm * 32 + i * 16 + qq * 4 + r;
          const int cc  = col0 + wn * 32 + j * 16 + colL;
          outRM[(size_t)row * CDIM + cc] = f2bf(acc[i][j][r] + bj[j]);
        }
  } else {
#pragma unroll
    for (int i = 0; i < 2; ++i)
#pragma unroll
      for (int j = 0; j < 2; ++j) {
        unsigned long long u =
            (unsigned long long)pack2(acc[i][j][0], acc[i][j][1]) |
            ((unsigned long long)pack2(acc[i][j][2], acc[i][j][3]) << 32);
        const int cc  = col0 + wn * 32 + j * 16 + colL;
        const int row = row0 + wm * 32 + i * 16 + qq * 4;   // 4-aligned key group
        *(unsigned long long*)&outTR[(size_t)cc * NROI + keypos(row)] = u;
      }
  }
}

// ---------------- MFMA flash attention, v3 ----------------
// 512 blocks x 512 threads (8 waves): 64 q-rows per block, two key-halves of
// 4 waves each with private double-buffered K/V staging. 2 blocks/CU ->
// two INDEPENDENT barrier domains per CU (fills barrier/drain stalls).
// XCD swizzle: groups {2x,2x+1} pinned to XCD x so the 64 resident blocks of
// an XCD share a ~1MB K/V working set in its 4MB L2.
// S^T = mfma(K,Q) keeps P in-lane (key-permuted V/bias); P packs via
// v_cvt_pk_bf16_f32; exp via v_exp_f32 with pre-folded 0.125*log2e.
__global__ __launch_bounds__(512, 4) void attn_bias(
    const short* __restrict__ Xb,             // (N,C) bf16 embedded x
    const short* __restrict__ ZTb,            // (C,N) bf16 V, transposed, key-permuted
    const unsigned short* __restrict__ biasb, // (N,N) bf16 iou+1e-6, key-permuted
    const float* __restrict__ bout,
    float* __restrict__ Out)
{
  // XCD-aware decode: lin%8 = XCD (HW round-robin). XCD x hosts groups 2x,2x+1.
  const int lin  = blockIdx.x + 32 * blockIdx.y;   // 512 blocks
  const int xcd  = lin & 7;
  const int slot = lin >> 3;                       // 0..63
  const int g    = 2 * xcd + (slot >> 5);
  const int n0   = (slot & 31) * 64;

  const int t    = threadIdx.x;
  const int w    = t >> 6;
  const int half = w >> 2;      // key half: 0 -> [0,1024), 1 -> [1024,2048)
  const int wq   = w & 3;       // q-tile index within block (16 q each)
  const int lane = t & 63;
  const int col  = lane & 15;
  const int qq   = lane >> 4;
  const int rlo  = col, khi = qq * 8;

  __shared__ short Kf[2][2][4096];  // [half][buf][frag]
  __shared__ short Vf[2][2][4096];

  const size_t qoff = (size_t)(n0 + wq * 16 + col) * CDIM + g * DH;
  const short8 qf0 = *(const short8*)(Xb + qoff + qq * 8);
  const short8 qf1 = *(const short8*)(Xb + qoff + 32 + qq * 8);

  floatx4 oc[4];
#pragma unroll
  for (int dt = 0; dt < 4; ++dt) oc[dt] = (floatx4){0.f, 0.f, 0.f, 0.f};
  float lsum = 0.f;

  const int mbase = half * 1024;
  // stage iter 0: wave wq stages K frags {2wq,2wq+1} (key-subtile wq, both
  // k-halves) and V frags {2wq,2wq+1} (d-subtile wq, both key-halves)
#pragma unroll
  for (int kh = 0; kh < 2; ++kh) {
    gl2lds16(Xb + (size_t)(mbase + wq * 16 + rlo) * CDIM + g * DH + kh * 32 + khi,
             &Kf[half][0][(wq * 2 + kh) * 512]);
    gl2lds16(ZTb + (size_t)(g * DH + wq * 16 + rlo) * NROI + mbase + kh * 32 + khi,
             &Vf[half][0][(wq * 2 + kh) * 512]);
  }
  __syncthreads();

  const unsigned short* bq =
      biasb + (size_t)(n0 + wq * 16 + col) * NROI + mbase + qq * 8;

  for (int it = 0; it < 16; ++it) {
    const int p  = it & 1;
    const int m0 = mbase + it * 64;

    // bias: two coalesced 16B loads (independent of QK -> issued early)
    union { short8 s[2]; unsigned short h[16]; } BU;
    BU.s[0] = *(const short8*)(bq + it * 64);
    BU.s[1] = *(const short8*)(bq + it * 64 + 32);

    if (it + 1 < 16) {
      const int m1 = m0 + 64;
#pragma unroll
      for (int kh = 0; kh < 2; ++kh) {
        gl2lds16(Xb + (size_t)(m1 + wq * 16 + rlo) * CDIM + g * DH + kh * 32 + khi,
                 &Kf[half][1 - p][(wq * 2 + kh) * 512]);
        gl2lds16(ZTb + (size_t)(g * DH + wq * 16 + rlo) * NROI + m1 + kh * 32 + khi,
                 &Vf[half][1 - p][(wq * 2 + kh) * 512]);
      }
    }

    // S^T = mfma(K, Q): lane holds S[key = m0+16ct+4qq+r][q = n0+wq*16+col]
    float e[4][4];
    __builtin_amdgcn_s_setprio(1);
#pragma unroll
    for (int ct = 0; ct < 4; ++ct) {
      const short8 k0 = *(const short8*)&Kf[half][p][(ct * 2 + 0) * 512 + lane * 8];
      const short8 k1 = *(const short8*)&Kf[half][p][(ct * 2 + 1) * 512 + lane * 8];
      floatx4 z4 = (floatx4){0.f, 0.f, 0.f, 0.f};
      z4 = MFMA_BF16(k0, qf0, z4);
      z4 = MFMA_BF16(k1, qf1, z4);
#pragma unroll
      for (int r = 0; r < 4; ++r) e[ct][r] = z4[r];
    }
    __builtin_amdgcn_s_setprio(0);

    // P = exp2(s * 0.125*log2e) * (iou+1e-6); accumulate row-sum
#pragma unroll
    for (int ct = 0; ct < 4; ++ct)
#pragma unroll
      for (int r = 0; r < 4; ++r) {
        const float pv = fexp2(e[ct][r] * 0.18033688011f) * bf2f(BU.h[ct * 4 + r]);
        e[ct][r] = pv;
        lsum += pv;
      }

    // pack in-lane into A-fragments (slot order matches permuted V)
    union { short8 s; unsigned u[4]; } U0, U1;
#pragma unroll
    for (int j = 0; j < 2; ++j) {
      U0.u[j * 2 + 0] = cvtpk_bf16(e[j][0], e[j][1]);
      U0.u[j * 2 + 1] = cvtpk_bf16(e[j][2], e[j][3]);
      U1.u[j * 2 + 0] = cvtpk_bf16(e[j + 2][0], e[j + 2][1]);
      U1.u[j * 2 + 1] = cvtpk_bf16(e[j + 2][2], e[j + 2][3]);
    }

    __builtin_amdgcn_s_setprio(1);
#pragma unroll
    for (int dt = 0; dt < 4; ++dt) {
      const short8 v0 = *(const short8*)&Vf[half][p][(dt * 2 + 0) * 512 + lane * 8];
      const short8 v1 = *(const short8*)&Vf[half][p][(dt * 2 + 1) * 512 + lane * 8];
      oc[dt] = MFMA_BF16(U0.s, v0, oc[dt]);
      oc[dt] = MFMA_BF16(U1.s, v1, oc[dt]);
    }
    __builtin_amdgcn_s_setprio(0);
    __syncthreads();
  }

  // lsum is per-lane over keys {16ct+4qq+r}: reduce across qq groups so every
  // lane holds the half-total for q = col
  float s = lsum;
  s += __shfl_xor(s, 16);
  s += __shfl_xor(s, 32);

  // combine the two key-halves through LDS (main loop done with K/V buffers)
  float* ocb = (float*)&Kf[0][0][0];   // 4096 floats = 4 waves * 64 lanes * 16
  float* lsb = (float*)&Vf[0][0][0];
  const int cbase = (wq * 64 + lane) * 16;
  if (half) {
#pragma unroll
    for (int dt = 0; dt < 4; ++dt)
#pragma unroll
      for (int r = 0; r < 4; ++r) ocb[cbase + dt * 4 + r] = oc[dt][r];
    lsb[wq * 64 + lane] = s;
  }
  __syncthreads();
  if (!half) {
    s += lsb[wq * 64 + lane];
    float ls[4], rinv[4];
#pragma unroll
    for (int r = 0; r < 4; ++r)
      ls[r] = __shfl(s, (qq << 4) | (qq * 4 + r));   // lsum for q-row qq*4+r
#pragma unroll
    for (int r = 0; r < 4; ++r)
      rinv[r] = __builtin_amdgcn_rcpf(ls[r]);
#pragma unroll
    for (int dt = 0; dt < 4; ++dt) {
      const float bo = bout[g * DH + dt * 16 + col];
#pragma unroll
      for (int r = 0; r < 4; ++r)
        Out[(size_t)(n0 + wq * 16 + qq * 4 + r) * CDIM + g * DH + dt * 16 + col] =
            (oc[dt][r] + ocb[cbase + dt * 4 + r]) * rinv[r] + bo;
    }
  }
}

extern "C" void kernel_launch(void* const* d_in, const int* in_sizes, int n_in,
                              void* d_out, int out_size, void* d_ws, size_t ws_size,
                              hipStream_t stream) {
  const float* in_x = (const float*)d_in[0];
  const float* rois = (const float*)d_in[1];
  const float* W0   = (const float*)d_in[2];
  const float* b0   = (const float*)d_in[3];
  const float* W1   = (const float*)d_in[4];
  const float* b1   = (const float*)d_in[5];
  const float* Wout = (const float*)d_in[6];  // (G,D,C) flat == (C,C) row-major
  const float* bout = (const float*)d_in[7];
  char* w8 = (char*)d_ws;

  // ws layout (22 MB):
  //   [0,4M)   xin_b (bf16 x) -> xb (gemm1 out; xin_b dead after gemm64<1>)
  //   [4,6M)   W0b   [6,8M) W1b   [8,10M) Woutb
  //   [10,14M) zT (bf16 V^T, key-permuted)
  //   [14,22M) biasb (bf16 iou+1e-6, key-permuted)
  short* xin_b = (short*)w8;
  short* W0b   = (short*)(w8 + ((size_t)4 << 20));
  short* W1b   = (short*)(w8 + ((size_t)6 << 20));
  short* Woutb = (short*)(w8 + ((size_t)8 << 20));
  short* zT    = (short*)(w8 + ((size_t)10 << 20));
  unsigned short* biasb = (unsigned short*)(w8 + ((size_t)14 << 20));
  short* xb  = xin_b;
  short* t0b = (short*)d_out;

  // 1) streaming converts
  convert_kernel<<<2048, 256, 0, stream>>>(in_x, W0, W1, Wout,
                                           xin_b, W0b, W1b, Woutb);
  // 2) iou bias matrix (key-permuted)
  iou4_kernel<<<dim3(2, NROI), 256, 0, stream>>>(rois, biasb);
  // 3) fused 64x64 high-occupancy: t0 = relu(x)@W0^T+b0 and zT = (x@Wout^T)^T
  gemm64<1><<<dim3(32, 32), 256, 0, stream>>>(xin_b, W0b, Woutb, b0, t0b, zT);
  // 4) 64x64 high-occupancy: xb = relu(t0)@W1^T + b1
  gemm64<0><<<dim3(16, 32), 256, 0, stream>>>(t0b, W1b, nullptr, b1, xb, nullptr);
  // 5) flash attention v3 (512 blocks x 8 waves, 2 barrier domains/CU)
  attn_bias<<<dim3(32, NG), 512, 0, stream>>>(xb, zT, biasb, bout,
                                              (float*)d_out);
}

// Round 3
// 180.184 us; speedup vs baseline: 1.0603x; 1.0603x over previous
//
#include <hip/hip_runtime.h>
#include <math.h>

// Problem constants
constexpr int NROI = 2048;  // N
constexpr int CDIM = 1024;  // C
constexpr int NG   = 16;    // groups
constexpr int DH   = 64;    // per-group dim

typedef __attribute__((ext_vector_type(8))) short short8;    // 8 bf16 (4 VGPRs)
typedef __attribute__((ext_vector_type(4))) float floatx4;   // MFMA C/D frag

#define MFMA_BF16(a, b, c) __builtin_amdgcn_mfma_f32_16x16x32_bf16((a), (b), (c), 0, 0, 0)

// fp32 -> bf16 round-to-nearest-even
__device__ __forceinline__ short f2bf(float f) {
  unsigned u = __float_as_uint(f);
  unsigned r = 0x7fffu + ((u >> 16) & 1u);
  return (short)((u + r) >> 16);
}
__device__ __forceinline__ float bf2f(unsigned short u) {
  return __uint_as_float(((unsigned)u) << 16);
}
__device__ __forceinline__ unsigned pack2(float a, float b) {
  return (unsigned)(unsigned short)f2bf(a) | ((unsigned)(unsigned short)f2bf(b) << 16);
}

// HW packed fp32->bf16 convert: dst.lo = bf16(lo), dst.hi = bf16(hi)
__device__ __forceinline__ unsigned cvtpk_bf16(float lo, float hi) {
  unsigned r;
  asm("v_cvt_pk_bf16_f32 %0, %1, %2" : "=v"(r) : "v"(lo), "v"(hi));
  return r;
}

// 2^x via v_exp_f32
__device__ __forceinline__ float fexp2(float x) {
#if __has_builtin(__builtin_amdgcn_exp2f)
  return __builtin_amdgcn_exp2f(x);
#else
  return __expf(x * 0.69314718056f);
#endif
}

// async global->LDS, 16B per lane; LDS dest = wave-uniform base + lane*16
typedef __attribute__((address_space(1))) void GV;
typedef __attribute__((address_space(3))) void LV;
__device__ __forceinline__ void gl2lds16(const void* g, void* l) {
  __builtin_amdgcn_global_load_lds((GV*)g, (LV*)l, 16, 0, 0);
}

// bf16 relu on a packed short8 (sign-bit based; exact)
__device__ __forceinline__ short8 brelu(short8 v) {
  union { short8 s; unsigned u[4]; } x; x.s = v;
#pragma unroll
  for (int i = 0; i < 4; ++i) {
    unsigned m = (x.u[i] >> 15) & 0x10001u;
    x.u[i] &= ~(m * 0xFFFFu);
  }
  return x.s;
}

// --- key-position permutation -------------------------------------------------
// The attention kernel computes S^T = mfma(K, Q), so a lane ends up holding
// P values for keys 16ct + 4qq + r. The PV contraction is invariant under a
// permutation of the MFMA k-slots, so we store V (zT) and the bias matrix with
// their key axis permuted such that P packs in-lane with NO cross-lane moves:
//   position p(k) within each 32-key block = ((k>>2)&3)*8 + ((k>>4)&1)*4 + (k&3)
// Groups of 4 consecutive keys (4-aligned) stay 4 consecutive positions, so the
// producers (gemm64's transposed store, iou4's uint2 store) just remap the
// store address at zero cost.
__device__ __forceinline__ int keypos(int k) {
  return (k & ~31) | (((k >> 2) & 3) << 3) | (((k >> 4) & 1) << 2);
}

// ---------------- streaming fp32 -> bf16 conversion (x + 3 weights) ----------------
__global__ __launch_bounds__(256) void convert_kernel(
    const float* __restrict__ in_x, const float* __restrict__ W0,
    const float* __restrict__ W1, const float* __restrict__ Wout,
    short* __restrict__ xin_b, short* __restrict__ W0b,
    short* __restrict__ W1b, short* __restrict__ Woutb)
{
  const int i = blockIdx.x * 256 + threadIdx.x;   // float4 units
  {
    const float4 v = ((const float4*)in_x)[i];
    uint2 u; u.x = pack2(v.x, v.y); u.y = pack2(v.z, v.w);
    ((uint2*)xin_b)[i] = u;
  }
  if (i < 262144) {
    float4 v = ((const float4*)W0)[i];
    uint2 u; u.x = pack2(v.x, v.y); u.y = pack2(v.z, v.w);
    ((uint2*)W0b)[i] = u;
    v = ((const float4*)W1)[i];
    u.x = pack2(v.x, v.y); u.y = pack2(v.z, v.w);
    ((uint2*)W1b)[i] = u;
    v = ((const float4*)Wout)[i];
    u.x = pack2(v.x, v.y); u.y = pack2(v.z, v.w);
    ((uint2*)Woutb)[i] = u;
  }
}

// ---------------- iou+1e-6 matrix, 4 keys/thread, rcp divide, 8-B stores ----------------
// Stores in KEY-PERMUTED layout (see keypos above).
__global__ __launch_bounds__(256) void iou4_kernel(const float* __restrict__ rois,
                                                   unsigned short* __restrict__ biasb)
{
  const int q  = blockIdx.y;
  const int k0 = (blockIdx.x * 256 + threadIdx.x) * 4;
  const float qx1 = rois[q * 5 + 1], qy1 = rois[q * 5 + 2];
  const float qx2 = rois[q * 5 + 3], qy2 = rois[q * 5 + 4];
  const float qa = (qx2 - qx1 + 1.f) * (qy2 - qy1 + 1.f);
  float v[4];
#pragma unroll
  for (int j = 0; j < 4; ++j) {
    const int k = k0 + j;
    const float kx1 = rois[k * 5 + 1], ky1 = rois[k * 5 + 2];
    const float kx2 = rois[k * 5 + 3], ky2 = rois[k * 5 + 4];
    const float ka = (kx2 - kx1 + 1.f) * (ky2 - ky1 + 1.f);
    float iw = fminf(qx2, kx2) - fmaxf(qx1, kx1) + 1.f;
    float ih = fminf(qy2, ky2) - fmaxf(qy1, ky1) + 1.f;
    iw = fmaxf(iw, 0.f); ih = fmaxf(ih, 0.f);
    const float inter = iw * ih;
    v[j] = inter * __builtin_amdgcn_rcpf(qa + ka - inter) + 1e-6f;
  }
  uint2 u; u.x = pack2(v[0], v[1]); u.y = pack2(v[2], v[3]);
  *(uint2*)&biasb[(size_t)q * NROI + keypos(k0)] = u;
}

// ---------------- 64x64 double-buffered GEMM, high occupancy ----------------
// FUSED=1: blockIdx.x<16 -> t0 = relu(x)@W0^T+b0 (row-major); else
//          zT = (x@Wout^T)^T (transposed out, KEY-PERMUTED rows). grid (32,32).
// FUSED=0: C = relu(A)@B^T + bias (row-major). grid (16,32).
template <int FUSED>
__global__ __launch_bounds__(256, 4) void gemm64(
    const short* __restrict__ A, const short* __restrict__ Ba,
    const short* __restrict__ Bb, const float* __restrict__ bias,
    short* __restrict__ outRM, short* __restrict__ outTR)
{
  __shared__ short As[2][8 * 512];
  __shared__ short Bs[2][8 * 512];
  const int t = threadIdx.x, w = t >> 6, lane = t & 63;
  const int wm = w >> 1, wn = w & 1;
  const int row0 = blockIdx.y * 64;
  bool isW0; int col0; const short* B;
  if (FUSED) {
    isW0 = blockIdx.x < 16;
    col0 = (blockIdx.x & 15) * 64;
    B = isW0 ? Ba : Bb;
  } else {
    isW0 = true; col0 = blockIdx.x * 64; B = Ba;
  }
  const bool doRelu = FUSED ? isW0 : true;
  const int rlo = lane & 15, khi = (lane >> 4) * 8;

  floatx4 acc[2][2];
#pragma unroll
  for (int i = 0; i < 2; ++i)
#pragma unroll
    for (int j = 0; j < 2; ++j) acc[i][j] = (floatx4){0.f, 0.f, 0.f, 0.f};

#pragma unroll
  for (int kh = 0; kh < 2; ++kh) {
    const int f = w * 2 + kh;
    gl2lds16(A + (size_t)(row0 + w * 16 + rlo) * CDIM + kh * 32 + khi, &As[0][f * 512]);
    gl2lds16(B + (size_t)(col0 + w * 16 + rlo) * CDIM + kh * 32 + khi, &Bs[0][f * 512]);
  }
  __syncthreads();

  for (int it = 0; it < 16; ++it) {
    const int p = it & 1;
    if (it < 15) {
      const int k1 = (it + 1) * 64;
#pragma unroll
      for (int kh = 0; kh < 2; ++kh) {
        const int f = w * 2 + kh;
        gl2lds16(A + (size_t)(row0 + w * 16 + rlo) * CDIM + k1 + kh * 32 + khi,
                 &As[1 - p][f * 512]);
        gl2lds16(B + (size_t)(col0 + w * 16 + rlo) * CDIM + k1 + kh * 32 + khi,
                 &Bs[1 - p][f * 512]);
      }
    }
#pragma unroll
    for (int kh = 0; kh < 2; ++kh) {
      short8 a[2], bf[2];
#pragma unroll
      for (int i = 0; i < 2; ++i) {
        a[i] = *(const short8*)&As[p][((wm * 2 + i) * 2 + kh) * 512 + lane * 8];
        if (doRelu) a[i] = brelu(a[i]);
      }
#pragma unroll
      for (int j = 0; j < 2; ++j)
        bf[j] = *(const short8*)&Bs[p][((wn * 2 + j) * 2 + kh) * 512 + lane * 8];
#pragma unroll
      for (int i = 0; i < 2; ++i)
#pragma unroll
        for (int j = 0; j < 2; ++j)
          acc[i][j] = MFMA_BF16(a[i], bf[j], acc[i][j]);
    }
    __syncthreads();
  }

  const int colL = lane & 15, qq = lane >> 4;
  if (!FUSED || isW0) {
    float bj[2];
    bj[0] = bias[col0 + wn * 32 + colL];
    bj[1] = bias[col0 + wn * 32 + 16 + colL];
#pragma unroll
    for (int i = 0; i < 2; ++i)
#pragma unroll
      for (int j = 0; j < 2; ++j)
#pragma unroll
        for (int r = 0; r < 4; ++r) {
          const int row = row0 + wm * 32 + i * 16 + qq * 4 + r;
          const int cc  = col0 + wn * 32 + j * 16 + colL;
          outRM[(size_t)row * CDIM + cc] = f2bf(acc[i][j][r] + bj[j]);
        }
  } else {
#pragma unroll
    for (int i = 0; i < 2; ++i)
#pragma unroll
      for (int j = 0; j < 2; ++j) {
        unsigned long long u =
            (unsigned long long)pack2(acc[i][j][0], acc[i][j][1]) |
            ((unsigned long long)pack2(acc[i][j][2], acc[i][j][3]) << 32);
        const int cc  = col0 + wn * 32 + j * 16 + colL;
        const int row = row0 + wm * 32 + i * 16 + qq * 4;   // 4-aligned key group
        *(unsigned long long*)&outTR[(size_t)cc * NROI + keypos(row)] = u;
      }
  }
}

// ---------------- MFMA flash attention, v4 ----------------
// 1024 threads = 16 waves = 4 key-quarters x 4 waves. Each wave computes
// 32 q-rows (two 16-q subtiles) so every K/V fragment read from LDS feeds
// 2 MFMAs -> LDS-read volume halved vs v2. Each quarter owns keys
// [qt*512,(qt+1)*512) with private double-buffered K/V staging -> only 8
// barrier-separated iterations (64 keys each). Block = 128 q rows, one group.
// Quarter partials (oc + lsum) combine once through LDS at the end
// (lane-contiguous [elem][wave][lane] layout, conflict-free).
// S^T = mfma(K,Q) keeps P in-lane (key-permuted V/bias); P packs via
// v_cvt_pk_bf16_f32 directly into A-fragments (no e[] array).
__global__ __launch_bounds__(1024) void attn_bias(
    const short* __restrict__ Xb,             // (N,C) bf16 embedded x
    const short* __restrict__ ZTb,            // (C,N) bf16 V, transposed, key-permuted
    const unsigned short* __restrict__ biasb, // (N,N) bf16 iou+1e-6, key-permuted
    const float* __restrict__ bout,
    float* __restrict__ Out)
{
  // XCD-aware decode: lin%8 = XCD. XCD x hosts groups {2x, 2x+1}.
  const int lin  = blockIdx.x + 16 * blockIdx.y;   // 256 blocks
  const int xcd  = lin & 7;
  const int slot = lin >> 3;                       // 0..31
  const int g    = 2 * xcd + (slot >> 4);
  const int n0   = (slot & 15) * 128;

  const int t    = threadIdx.x;
  const int w    = t >> 6;
  const int qt   = w >> 2;      // key quarter 0..3 -> keys [qt*512, qt*512+512)
  const int wq   = w & 3;       // q-pair index: q rows [n0+wq*32, n0+wq*32+32)
  const int lane = t & 63;
  const int col  = lane & 15;
  const int qq   = lane >> 4;
  const int rlo  = col, khi = qq * 8;

  __shared__ short Kq[4][2][4096];  // [quarter][buf][8 frags x 512]
  __shared__ short Vq[4][2][4096];

  // Q fragments for the two 16-q subtiles
  short8 qf[2][2];
#pragma unroll
  for (int s = 0; s < 2; ++s) {
    const size_t qoff = (size_t)(n0 + wq * 32 + s * 16 + col) * CDIM + g * DH;
    qf[s][0] = *(const short8*)(Xb + qoff + qq * 8);
    qf[s][1] = *(const short8*)(Xb + qoff + 32 + qq * 8);
  }

  floatx4 oc[2][4];   // [sub][dt]
#pragma unroll
  for (int s = 0; s < 2; ++s)
#pragma unroll
    for (int dt = 0; dt < 4; ++dt) oc[s][dt] = (floatx4){0.f, 0.f, 0.f, 0.f};
  float lsum[2] = {0.f, 0.f};

  const int kb = qt * 512;   // this quarter's key base

  // stage iter 0: wave wq stages key-subtile wq (both k/key halves)
#pragma unroll
  for (int kh = 0; kh < 2; ++kh) {
    gl2lds16(Xb + (size_t)(kb + wq * 16 + rlo) * CDIM + g * DH + kh * 32 + khi,
             &Kq[qt][0][(wq * 2 + kh) * 512]);
    gl2lds16(ZTb + (size_t)(g * DH + wq * 16 + rlo) * NROI + kb + kh * 32 + khi,
             &Vq[qt][0][(wq * 2 + kh) * 512]);
  }
  __syncthreads();

  const unsigned short* bq0 =
      biasb + (size_t)(n0 + wq * 32 + col) * NROI + kb + qq * 8;
  const unsigned short* bq1 = bq0 + (size_t)16 * NROI;

  for (int it = 0; it < 8; ++it) {
    const int p  = it & 1;
    const int m0 = kb + it * 64;

    // bias: four coalesced 16B loads (two per q-subtile), issued early
    union { short8 s8[4]; unsigned short h[32]; } BU;
    BU.s8[0] = *(const short8*)(bq0 + it * 64);
    BU.s8[1] = *(const short8*)(bq0 + it * 64 + 32);
    BU.s8[2] = *(const short8*)(bq1 + it * 64);
    BU.s8[3] = *(const short8*)(bq1 + it * 64 + 32);

    if (it + 1 < 8) {
      const int m1 = m0 + 64;
#pragma unroll
      for (int kh = 0; kh < 2; ++kh) {
        gl2lds16(Xb + (size_t)(m1 + wq * 16 + rlo) * CDIM + g * DH + kh * 32 + khi,
                 &Kq[qt][1 - p][(wq * 2 + kh) * 512]);
        gl2lds16(ZTb + (size_t)(g * DH + wq * 16 + rlo) * NROI + m1 + kh * 32 + khi,
                 &Vq[qt][1 - p][(wq * 2 + kh) * 512]);
      }
    }

    // QK + softmax-weight + pack, per 16-key column-tile ct; each K-frag pair
    // feeds BOTH q-subtiles (the LDS-read amortization).
    union { short8 s; unsigned u[4]; } U[2][2];   // [sub][kslot-half]
#pragma unroll
    for (int ct = 0; ct < 4; ++ct) {
      const short8 k0 = *(const short8*)&Kq[qt][p][(ct * 2 + 0) * 512 + lane * 8];
      const short8 k1 = *(const short8*)&Kq[qt][p][(ct * 2 + 1) * 512 + lane * 8];
#pragma unroll
      for (int s = 0; s < 2; ++s) {
        floatx4 z4 = (floatx4){0.f, 0.f, 0.f, 0.f};
        z4 = MFMA_BF16(k0, qf[s][0], z4);
        z4 = MFMA_BF16(k1, qf[s][1], z4);
        float pv0 = fexp2(z4[0] * 0.18033688011f) * bf2f(BU.h[s * 16 + ct * 4 + 0]);
        float pv1 = fexp2(z4[1] * 0.18033688011f) * bf2f(BU.h[s * 16 + ct * 4 + 1]);
        float pv2 = fexp2(z4[2] * 0.18033688011f) * bf2f(BU.h[s * 16 + ct * 4 + 2]);
        float pv3 = fexp2(z4[3] * 0.18033688011f) * bf2f(BU.h[s * 16 + ct * 4 + 3]);
        lsum[s] += (pv0 + pv1) + (pv2 + pv3);
        U[s][ct >> 1].u[(ct & 1) * 2 + 0] = cvtpk_bf16(pv0, pv1);
        U[s][ct >> 1].u[(ct & 1) * 2 + 1] = cvtpk_bf16(pv2, pv3);
      }
    }

    // PV: each V-frag pair feeds both q-subtiles
#pragma unroll
    for (int dt = 0; dt < 4; ++dt) {
      const short8 v0 = *(const short8*)&Vq[qt][p][(dt * 2 + 0) * 512 + lane * 8];
      const short8 v1 = *(const short8*)&Vq[qt][p][(dt * 2 + 1) * 512 + lane * 8];
#pragma unroll
      for (int s = 0; s < 2; ++s) {
        oc[s][dt] = MFMA_BF16(U[s][0].s, v0, oc[s][dt]);
        oc[s][dt] = MFMA_BF16(U[s][1].s, v1, oc[s][dt]);
      }
    }
    __syncthreads();
  }

  // per-quarter row sums: reduce across qq groups -> lane holds quarter-total
  // for q = n0 + wq*32 + s*16 + col
  float ssum[2];
#pragma unroll
  for (int s = 0; s < 2; ++s) {
    float x = lsum[s];
    x += __shfl_xor(x, 16);
    x += __shfl_xor(x, 32);
    ssum[s] = x;
  }

  // cross-quarter combine via LDS (K/V buffers dead). Lane-contiguous layout
  // [elem][wave12][lane]: sub0 oc -> Kq area, sub1 oc -> Vq area,
  // lsums -> Kq area after sub0 block. All strides lane-major: conflict-free.
  float* kbuf = (float*)&Kq[0][0][0];   // 16384 floats
  float* vbuf = (float*)&Vq[0][0][0];   // 16384 floats
  const int wslot = (qt - 1) * 4 + wq;  // 0..11 for quarters 1..3
  if (qt != 0) {
#pragma unroll
    for (int dt = 0; dt < 4; ++dt)
#pragma unroll
      for (int r = 0; r < 4; ++r) {
        kbuf[(dt * 4 + r) * 768 + wslot * 64 + lane] = oc[0][dt][r];
        vbuf[(dt * 4 + r) * 768 + wslot * 64 + lane] = oc[1][dt][r];
      }
    kbuf[12288 + (0 * 12 + wslot) * 64 + lane] = ssum[0];
    kbuf[12288 + (1 * 12 + wslot) * 64 + lane] = ssum[1];
  }
  __syncthreads();
  if (qt == 0) {
#pragma unroll
    for (int j = 0; j < 3; ++j) {
      const int ws = j * 4 + wq;
#pragma unroll
      for (int dt = 0; dt < 4; ++dt)
#pragma unroll
        for (int r = 0; r < 4; ++r) {
          oc[0][dt][r] += kbuf[(dt * 4 + r) * 768 + ws * 64 + lane];
          oc[1][dt][r] += vbuf[(dt * 4 + r) * 768 + ws * 64 + lane];
        }
      ssum[0] += kbuf[12288 + (0 * 12 + ws) * 64 + lane];
      ssum[1] += kbuf[12288 + (1 * 12 + ws) * 64 + lane];
    }
#pragma unroll
    for (int s = 0; s < 2; ++s) {
      float ls[4], rinv[4];
#pragma unroll
      for (int r = 0; r < 4; ++r)
        ls[r] = __shfl(ssum[s], (qq << 4) | (qq * 4 + r));  // total for q-row qq*4+r
#pragma unroll
      for (int r = 0; r < 4; ++r)
        rinv[r] = __builtin_amdgcn_rcpf(ls[r]);
#pragma unroll
      for (int dt = 0; dt < 4; ++dt) {
        const float bo = bout[g * DH + dt * 16 + col];
#pragma unroll
        for (int r = 0; r < 4; ++r)
          Out[(size_t)(n0 + wq * 32 + s * 16 + qq * 4 + r) * CDIM + g * DH +
              dt * 16 + col] = oc[s][dt][r] * rinv[r] + bo;
      }
    }
  }
}

extern "C" void kernel_launch(void* const* d_in, const int* in_sizes, int n_in,
                              void* d_out, int out_size, void* d_ws, size_t ws_size,
                              hipStream_t stream) {
  const float* in_x = (const float*)d_in[0];
  const float* rois = (const float*)d_in[1];
  const float* W0   = (const float*)d_in[2];
  const float* b0   = (const float*)d_in[3];
  const float* W1   = (const float*)d_in[4];
  const float* b1   = (const float*)d_in[5];
  const float* Wout = (const float*)d_in[6];  // (G,D,C) flat == (C,C) row-major
  const float* bout = (const float*)d_in[7];
  char* w8 = (char*)d_ws;

  // ws layout (22 MB):
  //   [0,4M)   xin_b (bf16 x) -> xb (gemm1 out; xin_b dead after gemm64<1>)
  //   [4,6M)   W0b   [6,8M) W1b   [8,10M) Woutb
  //   [10,14M) zT (bf16 V^T, key-permuted)
  //   [14,22M) biasb (bf16 iou+1e-6, key-permuted)
  short* xin_b = (short*)w8;
  short* W0b   = (short*)(w8 + ((size_t)4 << 20));
  short* W1b   = (short*)(w8 + ((size_t)6 << 20));
  short* Woutb = (short*)(w8 + ((size_t)8 << 20));
  short* zT    = (short*)(w8 + ((size_t)10 << 20));
  unsigned short* biasb = (unsigned short*)(w8 + ((size_t)14 << 20));
  short* xb  = xin_b;
  short* t0b = (short*)d_out;

  // 1) streaming converts
  convert_kernel<<<2048, 256, 0, stream>>>(in_x, W0, W1, Wout,
                                           xin_b, W0b, W1b, Woutb);
  // 2) iou bias matrix (key-permuted)
  iou4_kernel<<<dim3(2, NROI), 256, 0, stream>>>(rois, biasb);
  // 3) fused 64x64 high-occupancy: t0 = relu(x)@W0^T+b0 and zT = (x@Wout^T)^T
  gemm64<1><<<dim3(32, 32), 256, 0, stream>>>(xin_b, W0b, Woutb, b0, t0b, zT);
  // 4) 64x64 high-occupancy: xb = relu(t0)@W1^T + b1
  gemm64<0><<<dim3(16, 32), 256, 0, stream>>>(t0b, W1b, nullptr, b1, xb, nullptr);
  // 5) flash attention v4 (256 blocks x 16 waves, key-quarters, 32 q/wave)
  attn_bias<<<dim3(16, 16), 1024, 0, stream>>>(xb, zT, biasb, bout,
                                               (float*)d_out);
}

// Round 5
// 179.454 us; speedup vs baseline: 1.0646x; 1.0041x over previous
//
#include <hip/hip_runtime.h>
#include <math.h>

// Problem constants
constexpr int NROI = 2048;  // N
constexpr int CDIM = 1024;  // C
constexpr int NG   = 16;    // groups
constexpr int DH   = 64;    // per-group dim

typedef __attribute__((ext_vector_type(8))) short short8;    // 8 bf16 (4 VGPRs)
typedef __attribute__((ext_vector_type(4))) float floatx4;   // MFMA C/D frag

#define MFMA_BF16(a, b, c) __builtin_amdgcn_mfma_f32_16x16x32_bf16((a), (b), (c), 0, 0, 0)

// fp32 -> bf16 round-to-nearest-even
__device__ __forceinline__ short f2bf(float f) {
  unsigned u = __float_as_uint(f);
  unsigned r = 0x7fffu + ((u >> 16) & 1u);
  return (short)((u + r) >> 16);
}
__device__ __forceinline__ float bf2f(unsigned short u) {
  return __uint_as_float(((unsigned)u) << 16);
}
__device__ __forceinline__ unsigned pack2(float a, float b) {
  return (unsigned)(unsigned short)f2bf(a) | ((unsigned)(unsigned short)f2bf(b) << 16);
}

// HW packed fp32->bf16 convert: dst.lo = bf16(lo), dst.hi = bf16(hi)
__device__ __forceinline__ unsigned cvtpk_bf16(float lo, float hi) {
  unsigned r;
  asm("v_cvt_pk_bf16_f32 %0, %1, %2" : "=v"(r) : "v"(lo), "v"(hi));
  return r;
}

// 2^x via v_exp_f32
__device__ __forceinline__ float fexp2(float x) {
#if __has_builtin(__builtin_amdgcn_exp2f)
  return __builtin_amdgcn_exp2f(x);
#else
  return __expf(x * 0.69314718056f);
#endif
}

// async global->LDS, 16B per lane; LDS dest = wave-uniform base + lane*16
typedef __attribute__((address_space(1))) void GV;
typedef __attribute__((address_space(3))) void LV;
__device__ __forceinline__ void gl2lds16(const void* g, void* l) {
  __builtin_amdgcn_global_load_lds((GV*)g, (LV*)l, 16, 0, 0);
}

// bf16 relu on a packed short8 (sign-bit based; exact)
__device__ __forceinline__ short8 brelu(short8 v) {
  union { short8 s; unsigned u[4]; } x; x.s = v;
#pragma unroll
  for (int i = 0; i < 4; ++i) {
    unsigned m = (x.u[i] >> 15) & 0x10001u;
    x.u[i] &= ~(m * 0xFFFFu);
  }
  return x.s;
}

// --- key-position permutation -------------------------------------------------
// Attention computes S^T = mfma(K, Q); P stays in-lane. The PV contraction is
// invariant under k-slot permutation, so V (zT) and the bias matrix store their
// key axis permuted so P packs into A-fragments with no cross-lane moves:
//   position p(k) within each 32-key block = ((k>>2)&3)*8 + ((k>>4)&1)*4 + (k&3)
__device__ __forceinline__ int keypos(int k) {
  return (k & ~31) | (((k >> 2) & 3) << 3) | (((k >> 4) & 1) << 2);
}

// ---------------- prep: fp32->bf16 converts + iou bias (single launch) ----------------
// grid 2048 x 512. First 524288 threads convert x; first 262144 also convert the
// three weight matrices; ALL 1,048,576 threads compute 4 iou entries each and
// store iou + 1e-6 as bf16, KEY-PERMUTED (identical values to the verified
// iou4_kernel -- linear domain, same ops).
__global__ __launch_bounds__(512) void prep_kernel(
    const float* __restrict__ in_x, const float* __restrict__ W0,
    const float* __restrict__ W1, const float* __restrict__ Wout,
    const float* __restrict__ rois,
    short* __restrict__ xin_b, short* __restrict__ W0b,
    short* __restrict__ W1b, short* __restrict__ Woutb,
    unsigned short* __restrict__ biasb)
{
  const int gi = blockIdx.x * 512 + threadIdx.x;
  if (gi < 524288) {
    const float4 v = ((const float4*)in_x)[gi];
    uint2 u; u.x = pack2(v.x, v.y); u.y = pack2(v.z, v.w);
    ((uint2*)xin_b)[gi] = u;
  }
  if (gi < 262144) {
    float4 v = ((const float4*)W0)[gi];
    uint2 u; u.x = pack2(v.x, v.y); u.y = pack2(v.z, v.w);
    ((uint2*)W0b)[gi] = u;
    v = ((const float4*)W1)[gi];
    u.x = pack2(v.x, v.y); u.y = pack2(v.z, v.w);
    ((uint2*)W1b)[gi] = u;
    v = ((const float4*)Wout)[gi];
    u.x = pack2(v.x, v.y); u.y = pack2(v.z, v.w);
    ((uint2*)Woutb)[gi] = u;
  }
  // iou + 1e-6 (linear domain, verified math)
  const int q  = gi >> 9;
  const int k0 = (gi & 511) * 4;
  const float qx1 = rois[q * 5 + 1], qy1 = rois[q * 5 + 2];
  const float qx2 = rois[q * 5 + 3], qy2 = rois[q * 5 + 4];
  const float qa = (qx2 - qx1 + 1.f) * (qy2 - qy1 + 1.f);
  float v[4];
#pragma unroll
  for (int j = 0; j < 4; ++j) {
    const int k = k0 + j;
    const float kx1 = rois[k * 5 + 1], ky1 = rois[k * 5 + 2];
    const float kx2 = rois[k * 5 + 3], ky2 = rois[k * 5 + 4];
    const float ka = (kx2 - kx1 + 1.f) * (ky2 - ky1 + 1.f);
    float iw = fminf(qx2, kx2) - fmaxf(qx1, kx1) + 1.f;
    float ih = fminf(qy2, ky2) - fmaxf(qy1, ky1) + 1.f;
    iw = fmaxf(iw, 0.f); ih = fmaxf(ih, 0.f);
    const float inter = iw * ih;
    v[j] = inter * __builtin_amdgcn_rcpf(qa + ka - inter) + 1e-6f;
  }
  uint2 u; u.x = pack2(v[0], v[1]); u.y = pack2(v[2], v[3]);
  *(uint2*)&biasb[(size_t)q * NROI + keypos(k0)] = u;
}

// ---------------- 64x64 double-buffered GEMM, high occupancy ----------------
// FUSED=1: blockIdx.x<16 -> t0 = relu(x)@W0^T+b0 (row-major); else
//          zT = (x@Wout^T)^T (transposed out, KEY-PERMUTED rows). grid (32,32).
// FUSED=0: C = relu(A)@B^T + bias (row-major). grid (16,32).
template <int FUSED>
__global__ __launch_bounds__(256, 4) void gemm64(
    const short* __restrict__ A, const short* __restrict__ Ba,
    const short* __restrict__ Bb, const float* __restrict__ bias,
    short* __restrict__ outRM, short* __restrict__ outTR)
{
  __shared__ short As[2][8 * 512];
  __shared__ short Bs[2][8 * 512];
  const int t = threadIdx.x, w = t >> 6, lane = t & 63;
  const int wm = w >> 1, wn = w & 1;
  const int row0 = blockIdx.y * 64;
  bool isW0; int col0; const short* B;
  if (FUSED) {
    isW0 = blockIdx.x < 16;
    col0 = (blockIdx.x & 15) * 64;
    B = isW0 ? Ba : Bb;
  } else {
    isW0 = true; col0 = blockIdx.x * 64; B = Ba;
  }
  const bool doRelu = FUSED ? isW0 : true;
  const int rlo = lane & 15, khi = (lane >> 4) * 8;

  floatx4 acc[2][2];
#pragma unroll
  for (int i = 0; i < 2; ++i)
#pragma unroll
    for (int j = 0; j < 2; ++j) acc[i][j] = (floatx4){0.f, 0.f, 0.f, 0.f};

#pragma unroll
  for (int kh = 0; kh < 2; ++kh) {
    const int f = w * 2 + kh;
    gl2lds16(A + (size_t)(row0 + w * 16 + rlo) * CDIM + kh * 32 + khi, &As[0][f * 512]);
    gl2lds16(B + (size_t)(col0 + w * 16 + rlo) * CDIM + kh * 32 + khi, &Bs[0][f * 512]);
  }
  __syncthreads();

  for (int it = 0; it < 16; ++it) {
    const int p = it & 1;
    if (it < 15) {
      const int k1 = (it + 1) * 64;
#pragma unroll
      for (int kh = 0; kh < 2; ++kh) {
        const int f = w * 2 + kh;
        gl2lds16(A + (size_t)(row0 + w * 16 + rlo) * CDIM + k1 + kh * 32 + khi,
                 &As[1 - p][f * 512]);
        gl2lds16(B + (size_t)(col0 + w * 16 + rlo) * CDIM + k1 + kh * 32 + khi,
                 &Bs[1 - p][f * 512]);
      }
    }
#pragma unroll
    for (int kh = 0; kh < 2; ++kh) {
      short8 a[2], bf[2];
#pragma unroll
      for (int i = 0; i < 2; ++i) {
        a[i] = *(const short8*)&As[p][((wm * 2 + i) * 2 + kh) * 512 + lane * 8];
        if (doRelu) a[i] = brelu(a[i]);
      }
#pragma unroll
      for (int j = 0; j < 2; ++j)
        bf[j] = *(const short8*)&Bs[p][((wn * 2 + j) * 2 + kh) * 512 + lane * 8];
#pragma unroll
      for (int i = 0; i < 2; ++i)
#pragma unroll
        for (int j = 0; j < 2; ++j)
          acc[i][j] = MFMA_BF16(a[i], bf[j], acc[i][j]);
    }
    __syncthreads();
  }

  const int colL = lane & 15, qq = lane >> 4;
  if (!FUSED || isW0) {
    float bj[2];
    bj[0] = bias[col0 + wn * 32 + colL];
    bj[1] = bias[col0 + wn * 32 + 16 + colL];
#pragma unroll
    for (int i = 0; i < 2; ++i)
#pragma unroll
      for (int j = 0; j < 2; ++j)
#pragma unroll
        for (int r = 0; r < 4; ++r) {
          const int row = row0 + wm * 32 + i * 16 + qq * 4 + r;
          const int cc  = col0 + wn * 32 + j * 16 + colL;
          outRM[(size_t)row * CDIM + cc] = f2bf(acc[i][j][r] + bj[j]);
        }
  } else {
#pragma unroll
    for (int i = 0; i < 2; ++i)
#pragma unroll
      for (int j = 0; j < 2; ++j) {
        unsigned long long u =
            (unsigned long long)pack2(acc[i][j][0], acc[i][j][1]) |
            ((unsigned long long)pack2(acc[i][j][2], acc[i][j][3]) << 32);
        const int cc  = col0 + wn * 32 + j * 16 + colL;
        const int row = row0 + wm * 32 + i * 16 + qq * 4;   // 4-aligned key group
        *(unsigned long long*)&outTR[(size_t)cc * NROI + keypos(row)] = u;
      }
  }
}

// ---------------- MFMA flash attention, v4 (R3-verified, verbatim) ----------------
// 1024 threads = 16 waves = 4 key-quarters x 4 waves. Each wave computes
// 32 q-rows (two 16-q subtiles) so every K/V fragment read from LDS feeds
// 2 MFMAs. Each quarter owns keys [qt*512,(qt+1)*512) with private
// double-buffered K/V staging -> 8 barrier-separated iterations (64 keys each).
// Quarter partials (oc + lsum) combine once through LDS at the end.
__global__ __launch_bounds__(1024) void attn_bias(
    const short* __restrict__ Xb,             // (N,C) bf16 embedded x
    const short* __restrict__ ZTb,            // (C,N) bf16 V, transposed, key-permuted
    const unsigned short* __restrict__ biasb, // (N,N) bf16 iou+1e-6, key-permuted
    const float* __restrict__ bout,
    float* __restrict__ Out)
{
  // XCD-aware decode: lin%8 = XCD. XCD x hosts groups {2x, 2x+1}.
  const int lin  = blockIdx.x + 16 * blockIdx.y;   // 256 blocks
  const int xcd  = lin & 7;
  const int slot = lin >> 3;                       // 0..31
  const int g    = 2 * xcd + (slot >> 4);
  const int n0   = (slot & 15) * 128;

  const int t    = threadIdx.x;
  const int w    = t >> 6;
  const int qt   = w >> 2;      // key quarter 0..3 -> keys [qt*512, qt*512+512)
  const int wq   = w & 3;       // q-pair index: q rows [n0+wq*32, n0+wq*32+32)
  const int lane = t & 63;
  const int col  = lane & 15;
  const int qq   = lane >> 4;
  const int rlo  = col, khi = qq * 8;

  __shared__ short Kq[4][2][4096];  // [quarter][buf][8 frags x 512]
  __shared__ short Vq[4][2][4096];

  // Q fragments for the two 16-q subtiles
  short8 qf[2][2];
#pragma unroll
  for (int s = 0; s < 2; ++s) {
    const size_t qoff = (size_t)(n0 + wq * 32 + s * 16 + col) * CDIM + g * DH;
    qf[s][0] = *(const short8*)(Xb + qoff + qq * 8);
    qf[s][1] = *(const short8*)(Xb + qoff + 32 + qq * 8);
  }

  floatx4 oc[2][4];   // [sub][dt]
#pragma unroll
  for (int s = 0; s < 2; ++s)
#pragma unroll
    for (int dt = 0; dt < 4; ++dt) oc[s][dt] = (floatx4){0.f, 0.f, 0.f, 0.f};
  float lsum[2] = {0.f, 0.f};

  const int kb = qt * 512;   // this quarter's key base

  // stage iter 0: wave wq stages key-subtile wq (both k/key halves)
#pragma unroll
  for (int kh = 0; kh < 2; ++kh) {
    gl2lds16(Xb + (size_t)(kb + wq * 16 + rlo) * CDIM + g * DH + kh * 32 + khi,
             &Kq[qt][0][(wq * 2 + kh) * 512]);
    gl2lds16(ZTb + (size_t)(g * DH + wq * 16 + rlo) * NROI + kb + kh * 32 + khi,
             &Vq[qt][0][(wq * 2 + kh) * 512]);
  }
  __syncthreads();

  const unsigned short* bq0 =
      biasb + (size_t)(n0 + wq * 32 + col) * NROI + kb + qq * 8;
  const unsigned short* bq1 = bq0 + (size_t)16 * NROI;

  for (int it = 0; it < 8; ++it) {
    const int p  = it & 1;
    const int m0 = kb + it * 64;

    // bias: four coalesced 16B loads (two per q-subtile), issued early
    union { short8 s8[4]; unsigned short h[32]; } BU;
    BU.s8[0] = *(const short8*)(bq0 + it * 64);
    BU.s8[1] = *(const short8*)(bq0 + it * 64 + 32);
    BU.s8[2] = *(const short8*)(bq1 + it * 64);
    BU.s8[3] = *(const short8*)(bq1 + it * 64 + 32);

    if (it + 1 < 8) {
      const int m1 = m0 + 64;
#pragma unroll
      for (int kh = 0; kh < 2; ++kh) {
        gl2lds16(Xb + (size_t)(m1 + wq * 16 + rlo) * CDIM + g * DH + kh * 32 + khi,
                 &Kq[qt][1 - p][(wq * 2 + kh) * 512]);
        gl2lds16(ZTb + (size_t)(g * DH + wq * 16 + rlo) * NROI + m1 + kh * 32 + khi,
                 &Vq[qt][1 - p][(wq * 2 + kh) * 512]);
      }
    }

    // QK + softmax-weight + pack, per 16-key column-tile ct; each K-frag pair
    // feeds BOTH q-subtiles (the LDS-read amortization).
    union { short8 s; unsigned u[4]; } U[2][2];   // [sub][kslot-half]
#pragma unroll
    for (int ct = 0; ct < 4; ++ct) {
      const short8 k0 = *(const short8*)&Kq[qt][p][(ct * 2 + 0) * 512 + lane * 8];
      const short8 k1 = *(const short8*)&Kq[qt][p][(ct * 2 + 1) * 512 + lane * 8];
#pragma unroll
      for (int s = 0; s < 2; ++s) {
        floatx4 z4 = (floatx4){0.f, 0.f, 0.f, 0.f};
        z4 = MFMA_BF16(k0, qf[s][0], z4);
        z4 = MFMA_BF16(k1, qf[s][1], z4);
        float pv0 = fexp2(z4[0] * 0.18033688011f) * bf2f(BU.h[s * 16 + ct * 4 + 0]);
        float pv1 = fexp2(z4[1] * 0.18033688011f) * bf2f(BU.h[s * 16 + ct * 4 + 1]);
        float pv2 = fexp2(z4[2] * 0.18033688011f) * bf2f(BU.h[s * 16 + ct * 4 + 2]);
        float pv3 = fexp2(z4[3] * 0.18033688011f) * bf2f(BU.h[s * 16 + ct * 4 + 3]);
        lsum[s] += (pv0 + pv1) + (pv2 + pv3);
        U[s][ct >> 1].u[(ct & 1) * 2 + 0] = cvtpk_bf16(pv0, pv1);
        U[s][ct >> 1].u[(ct & 1) * 2 + 1] = cvtpk_bf16(pv2, pv3);
      }
    }

    // PV: each V-frag pair feeds both q-subtiles
#pragma unroll
    for (int dt = 0; dt < 4; ++dt) {
      const short8 v0 = *(const short8*)&Vq[qt][p][(dt * 2 + 0) * 512 + lane * 8];
      const short8 v1 = *(const short8*)&Vq[qt][p][(dt * 2 + 1) * 512 + lane * 8];
#pragma unroll
      for (int s = 0; s < 2; ++s) {
        oc[s][dt] = MFMA_BF16(U[s][0].s, v0, oc[s][dt]);
        oc[s][dt] = MFMA_BF16(U[s][1].s, v1, oc[s][dt]);
      }
    }
    __syncthreads();
  }

  // per-quarter row sums: reduce across qq groups -> lane holds quarter-total
  // for q = n0 + wq*32 + s*16 + col
  float ssum[2];
#pragma unroll
  for (int s = 0; s < 2; ++s) {
    float x = lsum[s];
    x += __shfl_xor(x, 16);
    x += __shfl_xor(x, 32);
    ssum[s] = x;
  }

  // cross-quarter combine via LDS (K/V buffers dead). Lane-contiguous layout
  // [elem][wave12][lane]: sub0 oc -> Kq area, sub1 oc -> Vq area,
  // lsums -> Kq area after sub0 block. All strides lane-major: conflict-free.
  float* kbuf = (float*)&Kq[0][0][0];   // 16384 floats
  float* vbuf = (float*)&Vq[0][0][0];   // 16384 floats
  const int wslot = (qt - 1) * 4 + wq;  // 0..11 for quarters 1..3
  if (qt != 0) {
#pragma unroll
    for (int dt = 0; dt < 4; ++dt)
#pragma unroll
      for (int r = 0; r < 4; ++r) {
        kbuf[(dt * 4 + r) * 768 + wslot * 64 + lane] = oc[0][dt][r];
        vbuf[(dt * 4 + r) * 768 + wslot * 64 + lane] = oc[1][dt][r];
      }
    kbuf[12288 + (0 * 12 + wslot) * 64 + lane] = ssum[0];
    kbuf[12288 + (1 * 12 + wslot) * 64 + lane] = ssum[1];
  }
  __syncthreads();
  if (qt == 0) {
#pragma unroll
    for (int j = 0; j < 3; ++j) {
      const int ws = j * 4 + wq;
#pragma unroll
      for (int dt = 0; dt < 4; ++dt)
#pragma unroll
        for (int r = 0; r < 4; ++r) {
          oc[0][dt][r] += kbuf[(dt * 4 + r) * 768 + ws * 64 + lane];
          oc[1][dt][r] += vbuf[(dt * 4 + r) * 768 + ws * 64 + lane];
        }
      ssum[0] += kbuf[12288 + (0 * 12 + ws) * 64 + lane];
      ssum[1] += kbuf[12288 + (1 * 12 + ws) * 64 + lane];
    }
#pragma unroll
    for (int s = 0; s < 2; ++s) {
      float ls[4], rinv[4];
#pragma unroll
      for (int r = 0; r < 4; ++r)
        ls[r] = __shfl(ssum[s], (qq << 4) | (qq * 4 + r));  // total for q-row qq*4+r
#pragma unroll
      for (int r = 0; r < 4; ++r)
        rinv[r] = __builtin_amdgcn_rcpf(ls[r]);
#pragma unroll
      for (int dt = 0; dt < 4; ++dt) {
        const float bo = bout[g * DH + dt * 16 + col];
#pragma unroll
        for (int r = 0; r < 4; ++r)
          Out[(size_t)(n0 + wq * 32 + s * 16 + qq * 4 + r) * CDIM + g * DH +
              dt * 16 + col] = oc[s][dt][r] * rinv[r] + bo;
      }
    }
  }
}

extern "C" void kernel_launch(void* const* d_in, const int* in_sizes, int n_in,
                              void* d_out, int out_size, void* d_ws, size_t ws_size,
                              hipStream_t stream) {
  const float* in_x = (const float*)d_in[0];
  const float* rois = (const float*)d_in[1];
  const float* W0   = (const float*)d_in[2];
  const float* b0   = (const float*)d_in[3];
  const float* W1   = (const float*)d_in[4];
  const float* b1   = (const float*)d_in[5];
  const float* Wout = (const float*)d_in[6];  // (G,D,C) flat == (C,C) row-major
  const float* bout = (const float*)d_in[7];
  char* w8 = (char*)d_ws;

  // ws layout (22 MB):
  //   [0,4M)   xin_b (bf16 x) -> xb (gemm1 out; xin_b dead after gemm64<1>)
  //   [4,6M)   W0b   [6,8M) W1b   [8,10M) Woutb
  //   [10,14M) zT (bf16 V^T, key-permuted)
  //   [14,22M) biasb (bf16 iou+1e-6, key-permuted)
  short* xin_b = (short*)w8;
  short* W0b   = (short*)(w8 + ((size_t)4 << 20));
  short* W1b   = (short*)(w8 + ((size_t)6 << 20));
  short* Woutb = (short*)(w8 + ((size_t)8 << 20));
  short* zT    = (short*)(w8 + ((size_t)10 << 20));
  unsigned short* biasb = (unsigned short*)(w8 + ((size_t)14 << 20));
  short* xb  = xin_b;
  short* t0b = (short*)d_out;

  // 1) merged converts + iou bias (one launch, linear domain -- verified math)
  prep_kernel<<<2048, 512, 0, stream>>>(in_x, W0, W1, Wout, rois,
                                        xin_b, W0b, W1b, Woutb, biasb);
  // 2) fused 64x64 high-occupancy: t0 = relu(x)@W0^T+b0 and zT = (x@Wout^T)^T
  gemm64<1><<<dim3(32, 32), 256, 0, stream>>>(xin_b, W0b, Woutb, b0, t0b, zT);
  // 3) 64x64 high-occupancy: xb = relu(t0)@W1^T + b1
  gemm64<0><<<dim3(16, 32), 256, 0, stream>>>(t0b, W1b, nullptr, b1, xb, nullptr);
  // 4) flash attention v4 (R3-verified verbatim)
  attn_bias<<<dim3(16, 16), 1024, 0, stream>>>(xb, zT, biasb, bout,
                                               (float*)d_out);
}